// Round 2
// baseline (5491.992 us; speedup 1.0000x reference)
//
#include <hip/hip_runtime.h>
#include <math.h>

#define Bn 32
#define Tn 64
#define Fdim 32
#define Gdim 32
#define Hdim 256
#define Ndim 20000
#define Cdim 32
#define G4 1024      // 4*H
#define BT 2048      // B*T
#define EPSc 1e-5f

__device__ __forceinline__ float sigmoidf_(float x){ return 1.0f/(1.0f + __expf(-x)); }
__device__ __forceinline__ float tanhf_(float x){ return 2.0f/(1.0f+__expf(-2.0f*x)) - 1.0f; }

// ---- init workspace stats + lookup table -------------------------------
__global__ void init_kernel(float* ws){
  int i = blockIdx.x*256 + threadIdx.x;
  if (i < 2112) ws[i] = 0.0f;                  // gat stats (64) + bn stats (4*512)
  int* table = (int*)(ws + 2112);
  if (i < 40000) table[i] = 0x7fffffff;
}

// ---- gat_output mean/var reduction -------------------------------------
__global__ void bn_stats_kernel(const float* __restrict__ gat, float* __restrict__ sums){
  __shared__ float ss[256], sq[256];
  int tid = threadIdx.x;
  int idx = blockIdx.x*256 + tid;
  int stride = gridDim.x*256;
  const int total = Bn*Ndim*Gdim; // 20,480,000
  float s=0.f,q=0.f;
  for (int i=idx; i<total; i+=stride){ float v = gat[i]; s+=v; q+=v*v; }
  ss[tid]=s; sq[tid]=q; __syncthreads();
  for (int off=128; off>=32; off>>=1){
    if(tid<off){ ss[tid]+=ss[tid+off]; sq[tid]+=sq[tid+off]; }
    __syncthreads();
  }
  if (tid<32){ atomicAdd(&sums[tid], ss[tid]); atomicAdd(&sums[32+tid], sq[tid]); }
}

// ---- node id -> first index table --------------------------------------
__global__ void table_kernel(const int* __restrict__ node_ids, int* __restrict__ table){
  int i = blockIdx.x*256 + threadIdx.x;
  if (i < Ndim) atomicMin(&table[node_ids[i]], i);
}

// ---- gather + normalize + concat -> lstm_in (BT,64) --------------------
__global__ void build_input_kernel(const float* __restrict__ feats, const float* __restrict__ gat,
    const int* __restrict__ row_ids, const int* __restrict__ table, const float* __restrict__ sums,
    const float* __restrict__ bng, const float* __restrict__ bnb, float* __restrict__ out){
  int gt = blockIdx.x*256 + threadIdx.x;     // BT*64 total
  int pos = gt >> 6; int lane = gt & 63;
  float v;
  if (lane < 32){
    v = feats[pos*Fdim + lane];
  } else {
    int g = lane - 32;
    int r = row_ids[pos];
    int idx = table[r];
    if (idx < Ndim){
      int b = pos / Tn;
      float x = gat[(b*Ndim + idx)*Gdim + g];
      const float cnt = (float)(Bn*Ndim);
      float mean = sums[g]/cnt;
      float var  = sums[32+g]/cnt - mean*mean;
      v = (x-mean)*bng[g]*rsqrtf(var+EPSc) + bnb[g];
    } else v = 0.0f;
  }
  out[gt] = v;
}

// ---- transpose all weight matrices (1024,K) -> (K,1024) ----------------
struct TArgs { const float* src[16]; float* dst[16]; int K[16]; };
__global__ void transpose_kernel(TArgs a){
  __shared__ float tile[32][33];
  int mat = blockIdx.y;
  int K = a.K[mat];
  int tc = blockIdx.x & 7; int tr = blockIdx.x >> 3;   // gridDim.x = 256
  if (tc*32 >= K) return;
  const float* src = a.src[mat]; float* dst = a.dst[mat];
  int tx = threadIdx.x; int ty = threadIdx.y;          // 32 x 8
  int r0 = tr*32, c0 = tc*32;
  #pragma unroll
  for (int i=0;i<4;i++){ int r = ty + i*8; tile[r][tx] = src[(r0+r)*K + c0+tx]; }
  __syncthreads();
  #pragma unroll
  for (int i=0;i<4;i++){ int r = ty + i*8; dst[(c0 + r)*G4 + r0 + tx] = tile[tx][r]; }
}

// ---- input projection: out(m,1024) = x(m,K) @ WT(K,1024) + bias --------
struct PArgs { const float* x[3]; const float* wt[3]; const float* bias[3]; float* out[3]; int K; };
__global__ __launch_bounds__(256) void proj_kernel(PArgs a){
  int hd = blockIdx.z;
  int j  = blockIdx.y*256 + threadIdx.x;
  int m0 = blockIdx.x*4;
  const float* x  = a.x[hd];
  const float* wt = a.wt[hd];
  int K = a.K;
  float bv = a.bias[hd][j];
  float acc0=bv, acc1=bv, acc2=bv, acc3=bv;
  const float* x0 = x + m0*K;   // uniform addresses -> scalar loads
  #pragma unroll 4
  for (int k=0;k<K;k++){
    float w = wt[k*G4 + j];
    acc0 = fmaf(x0[k],     w, acc0);
    acc1 = fmaf(x0[K+k],   w, acc1);
    acc2 = fmaf(x0[2*K+k], w, acc2);
    acc3 = fmaf(x0[3*K+k], w, acc3);
  }
  float* out = a.out[hd] + m0*G4 + j;
  out[0]=acc0; out[G4]=acc1; out[2*G4]=acc2; out[3*G4]=acc3;
}

// ---- LSTM recurrence: one block per (batch, head) ----------------------
// 1024 threads. thread (j = tid&255, kq = tid>>8) owns outputs 4j..4j+3
// for k-slice [64kq, 64kq+64). Entire Whh^T (1 MB) lives in VGPRs:
// 64 float4 = 256 regs/thread x 1024 threads. Per step: broadcast h reads
// from LDS, 256 reg-FMAs, partials to LDS, 4-way reduce + activations.
struct RArgs { const float* xp[3]; const float* wt[3]; float* out[3]; };
__global__ __launch_bounds__(1024) void rec_kernel(RArgs a){
  int b = blockIdx.x; int hd = blockIdx.y; int tid = threadIdx.x;
  int j  = tid & 255;
  int kq = tid >> 8;
  const float* xp = a.xp[hd] + (size_t)b*Tn*G4;
  const float* wt = a.wt[hd];
  float* out = a.out[hd] + (size_t)b*Tn*Hdim;
  __shared__ float hbuf[2][Hdim];
  __shared__ float part[4*G4];       // 16 KB partials
  const int k0 = kq*64;
  // preload weight slice into registers (one coalesced pass, amortized over 64 steps)
  float4 w[64];
  #pragma unroll
  for (int kk=0; kk<64; kk++)
    w[kk] = *(const float4*)(wt + (size_t)(k0+kk)*G4 + 4*j);
  float c = 0.0f;
  if (tid < Hdim) hbuf[0][tid] = 0.0f;
  __syncthreads();
  int p = 0;
  for (int t=0; t<Tn; t++){
    float4 acc;
    if (kq == 0) acc = *(const float4*)(xp + t*G4 + 4*j);
    else         acc = make_float4(0.f,0.f,0.f,0.f);
    const float* hrow = hbuf[p] + k0;
    #pragma unroll
    for (int kk=0; kk<16; kk++){
      float4 hv = *(const float4*)(hrow + 4*kk);   // wave-uniform -> LDS broadcast
      float4 w0 = w[4*kk+0], w1 = w[4*kk+1], w2 = w[4*kk+2], w3 = w[4*kk+3];
      acc.x = fmaf(w0.x,hv.x,acc.x); acc.y = fmaf(w0.y,hv.x,acc.y);
      acc.z = fmaf(w0.z,hv.x,acc.z); acc.w = fmaf(w0.w,hv.x,acc.w);
      acc.x = fmaf(w1.x,hv.y,acc.x); acc.y = fmaf(w1.y,hv.y,acc.y);
      acc.z = fmaf(w1.z,hv.y,acc.z); acc.w = fmaf(w1.w,hv.y,acc.w);
      acc.x = fmaf(w2.x,hv.z,acc.x); acc.y = fmaf(w2.y,hv.z,acc.y);
      acc.z = fmaf(w2.z,hv.z,acc.z); acc.w = fmaf(w2.w,hv.z,acc.w);
      acc.x = fmaf(w3.x,hv.w,acc.x); acc.y = fmaf(w3.y,hv.w,acc.y);
      acc.z = fmaf(w3.z,hv.w,acc.z); acc.w = fmaf(w3.w,hv.w,acc.w);
    }
    *(float4*)(part + kq*G4 + 4*j) = acc;
    __syncthreads();
    if (tid < Hdim){
      int u = tid;
      float gi = part[u]       + part[G4+u]       + part[2*G4+u]       + part[3*G4+u];
      float gf = part[256+u]   + part[G4+256+u]   + part[2*G4+256+u]   + part[3*G4+256+u];
      float gg = part[512+u]   + part[G4+512+u]   + part[2*G4+512+u]   + part[3*G4+512+u];
      float go = part[768+u]   + part[G4+768+u]   + part[2*G4+768+u]   + part[3*G4+768+u];
      c = sigmoidf_(gf)*c + sigmoidf_(gi)*tanhf_(gg);
      float h = sigmoidf_(go)*tanhf_(c);
      out[t*Hdim + u] = h;
      hbuf[p^1][u] = h;
    }
    __syncthreads();
    p ^= 1;
  }
}

// ---- per-feature mean/var stats over (B,T) -----------------------------
struct SArgs { const float* in[3]; float* stats[3]; };
__global__ void stats_kernel(SArgs a){
  int hd = blockIdx.y; int tid = threadIdx.x;
  const float* in = a.in[hd] + blockIdx.x*256*Hdim;
  float s=0.f,q=0.f;
  for (int r=0;r<256;r++){ float v = in[r*Hdim + tid]; s+=v; q+=v*v; }
  atomicAdd(&a.stats[hd][tid], s);
  atomicAdd(&a.stats[hd][Hdim+tid], q);
}

// ---- normalize shared output ------------------------------------------
__global__ void norm_kernel(const float* __restrict__ in, const float* __restrict__ stats,
   const float* __restrict__ g, const float* __restrict__ bta, float* __restrict__ out){
  int i = blockIdx.x*256 + threadIdx.x;
  int h = i & 255;
  float mean = stats[h]*(1.0f/BT);
  float var  = stats[Hdim+h]*(1.0f/BT) - mean*mean;
  out[i] = (in[i]-mean)*g[h]*rsqrtf(var+EPSc) + bta[h];
}

// ---- final: normalize last step of heads, fc + softmax -----------------
__global__ __launch_bounds__(256) void final_kernel(
  const float* __restrict__ h0, const float* __restrict__ h1, const float* __restrict__ h2,
  const float* __restrict__ stats,    // base ws+S_BN; head hd at (1+hd)*512
  const float* __restrict__ hbg, const float* __restrict__ hbb,
  const float* __restrict__ actW, const float* __restrict__ actB,
  const float* __restrict__ tW, const float* __restrict__ tB,
  const float* __restrict__ rW, const float* __restrict__ rB,
  float* __restrict__ outp){
  __shared__ float v0[Bn*Hdim];
  __shared__ float lg[Bn*Cdim];
  int tid = threadIdx.x;
  for (int i=tid; i<Bn*Hdim; i+=256){
    int b=i>>8, h=i&255;
    float sm = stats[512 + h], sq = stats[512+256+h];
    float mean = sm*(1.0f/BT); float var = sq*(1.0f/BT) - mean*mean;
    v0[i] = (h0[(b*Tn+63)*Hdim + h] - mean)*hbg[h]*rsqrtf(var+EPSc) + hbb[h];
  }
  __syncthreads();
  for (int i=tid; i<Bn*Cdim; i+=256){
    int b=i>>5, cc=i&31;
    float acc = actB[cc];
    const float* wrow = actW + cc*Hdim;
    const float* vrow = v0 + b*Hdim;
    #pragma unroll 4
    for (int h=0;h<Hdim;h++) acc = fmaf(vrow[h], wrow[h], acc);
    lg[i] = acc;
  }
  __syncthreads();
  if (tid < Bn){
    int b = tid;
    float m = -1e30f;
    #pragma unroll
    for (int cc=0; cc<Cdim; cc++) m = fmaxf(m, lg[b*Cdim+cc]);
    float e[Cdim]; float s = 0.f;
    #pragma unroll
    for (int cc=0; cc<Cdim; cc++){ float ee = __expf(lg[b*Cdim+cc]-m); e[cc]=ee; s+=ee; }
    float inv = 1.0f/s;
    #pragma unroll
    for (int cc=0; cc<Cdim; cc++) outp[b*Cdim+cc] = e[cc]*inv;
  }
  if (tid < 64){
    int b = tid & 31; int w = tid >> 5;
    const float* hh = w ? h2 : h1;
    const float* fw = w ? rW : tW;
    float fb = w ? rB[0] : tB[0];
    int hd = 1 + w;
    float acc = fb;
    for (int h=0; h<Hdim; h++){
      float sm = stats[(1+hd)*512 + h], sq = stats[(1+hd)*512+256+h];
      float mean = sm*(1.0f/BT); float var = sq*(1.0f/BT) - mean*mean;
      float v = (hh[(b*Tn+63)*Hdim + h] - mean)*hbg[hd*Hdim+h]*rsqrtf(var+EPSc) + hbb[hd*Hdim+h];
      acc = fmaf(v, fw[h], acc);
    }
    outp[1024 + w*32 + b] = acc;
  }
}

extern "C" void kernel_launch(void* const* d_in, const int* in_sizes, int n_in,
                              void* d_out, int out_size, void* d_ws, size_t ws_size,
                              hipStream_t stream){
  const float* data_feats = (const float*)d_in[0];
  const float* gat   = (const float*)d_in[1];
  const int*   row_ids  = (const int*)d_in[2];
  const int*   node_ids = (const int*)d_in[3];
  const float* sWih0 = (const float*)d_in[4];
  const float* sWhh0 = (const float*)d_in[5];
  const float* sb0   = (const float*)d_in[6];
  const float* sWih1 = (const float*)d_in[7];
  const float* sWhh1 = (const float*)d_in[8];
  const float* sb1   = (const float*)d_in[9];
  const float* hWih  = (const float*)d_in[10];
  const float* hWhh  = (const float*)d_in[11];
  const float* hb    = (const float*)d_in[12];
  const float* bng   = (const float*)d_in[13];
  const float* bnb   = (const float*)d_in[14];
  const float* bsg   = (const float*)d_in[15];
  const float* bsb   = (const float*)d_in[16];
  const float* hbg   = (const float*)d_in[17];
  const float* hbb   = (const float*)d_in[18];
  const float* actW  = (const float*)d_in[19];
  const float* actB  = (const float*)d_in[20];
  const float* tW    = (const float*)d_in[21];
  const float* tB    = (const float*)d_in[22];
  const float* rW    = (const float*)d_in[23];
  const float* rB    = (const float*)d_in[24];
  float* ws  = (float*)d_ws;
  float* out = (float*)d_out;

  // workspace layout (float offsets)
  const size_t S_GAT = 0;                       // 64
  const size_t S_BN  = 64;                      // 4*512
  const size_t TABLE = 2112;                    // 40000 ints
  const size_t TWOFF = 42112;                   // 16 slots x 262144
  const size_t SLOT  = 262144;
  const size_t LSTM_IN = TWOFF + 16*SLOT;       // 4,236,416
  const size_t XPOFF   = LSTM_IN + 131072;      // 3 x 2,097,152
  const size_t BUF0 = XPOFF + 3*2097152;
  const size_t BUF1 = BUF0 + 524288;
  const size_t BUFN = BUF1 + 524288;
  const size_t HB0  = BUFN + 524288;
  const size_t HB1  = HB0 + 3*524288;           // end = HB1 + 3*524288 = 15,377,536 floats

  init_kernel<<<157,256,0,stream>>>(ws);
  bn_stats_kernel<<<2048,256,0,stream>>>(gat, ws+S_GAT);
  table_kernel<<<(Ndim+255)/256,256,0,stream>>>(node_ids, (int*)(ws+TABLE));
  build_input_kernel<<<512,256,0,stream>>>(data_feats, gat, row_ids, (int*)(ws+TABLE),
                                           ws+S_GAT, bng, bnb, ws+LSTM_IN);

  TArgs ta;
  float* tw = ws + TWOFF;
  ta.src[0]=sWih0; ta.K[0]=64;
  ta.src[1]=sWhh0; ta.K[1]=256;
  ta.src[2]=sWih1; ta.K[2]=256;
  ta.src[3]=sWhh1; ta.K[3]=256;
  for (int hd=0; hd<3; hd++) for (int l=0;l<2;l++){
    ta.src[4+hd*2+l]  = hWih + (size_t)(hd*2+l)*G4*Hdim; ta.K[4+hd*2+l]  = 256;
    ta.src[10+hd*2+l] = hWhh + (size_t)(hd*2+l)*G4*Hdim; ta.K[10+hd*2+l] = 256;
  }
  for (int i=0;i<16;i++) ta.dst[i] = tw + i*SLOT;
  transpose_kernel<<<dim3(256,16),dim3(32,8),0,stream>>>(ta);

  PArgs pa; RArgs ra; SArgs sa;
  // shared layer 0
  pa.K=64; pa.x[0]=ws+LSTM_IN; pa.wt[0]=tw+0*SLOT; pa.bias[0]=sb0; pa.out[0]=ws+XPOFF;
  proj_kernel<<<dim3(512,4,1),256,0,stream>>>(pa);
  ra.xp[0]=ws+XPOFF; ra.wt[0]=tw+1*SLOT; ra.out[0]=ws+BUF0;
  rec_kernel<<<dim3(32,1),1024,0,stream>>>(ra);
  // shared layer 1
  pa.K=256; pa.x[0]=ws+BUF0; pa.wt[0]=tw+2*SLOT; pa.bias[0]=sb1; pa.out[0]=ws+XPOFF;
  proj_kernel<<<dim3(512,4,1),256,0,stream>>>(pa);
  ra.xp[0]=ws+XPOFF; ra.wt[0]=tw+3*SLOT; ra.out[0]=ws+BUF1;
  rec_kernel<<<dim3(32,1),1024,0,stream>>>(ra);
  // shared batchnorm
  sa.in[0]=ws+BUF1; sa.stats[0]=ws+S_BN;
  stats_kernel<<<dim3(8,1),256,0,stream>>>(sa);
  norm_kernel<<<2048,256,0,stream>>>(ws+BUF1, ws+S_BN, bsg, bsb, ws+BUFN);
  // heads layer 0
  pa.K=256;
  for (int hd=0;hd<3;hd++){
    pa.x[hd]=ws+BUFN; pa.wt[hd]=tw+(4+hd*2)*SLOT; pa.bias[hd]=hb + (size_t)(hd*2)*G4;
    pa.out[hd]=ws+XPOFF+(size_t)hd*2097152;
  }
  proj_kernel<<<dim3(512,4,3),256,0,stream>>>(pa);
  for (int hd=0;hd<3;hd++){
    ra.xp[hd]=ws+XPOFF+(size_t)hd*2097152; ra.wt[hd]=tw+(10+hd*2)*SLOT; ra.out[hd]=ws+HB0+(size_t)hd*524288;
  }
  rec_kernel<<<dim3(32,3),1024,0,stream>>>(ra);
  // heads layer 1
  for (int hd=0;hd<3;hd++){
    pa.x[hd]=ws+HB0+(size_t)hd*524288; pa.wt[hd]=tw+(4+hd*2+1)*SLOT; pa.bias[hd]=hb + (size_t)(hd*2+1)*G4;
    pa.out[hd]=ws+XPOFF+(size_t)hd*2097152;
  }
  proj_kernel<<<dim3(512,4,3),256,0,stream>>>(pa);
  for (int hd=0;hd<3;hd++){
    ra.xp[hd]=ws+XPOFF+(size_t)hd*2097152; ra.wt[hd]=tw+(10+hd*2+1)*SLOT; ra.out[hd]=ws+HB1+(size_t)hd*524288;
  }
  rec_kernel<<<dim3(32,3),1024,0,stream>>>(ra);
  // heads batchnorm stats
  for (int hd=0;hd<3;hd++){ sa.in[hd]=ws+HB1+(size_t)hd*524288; sa.stats[hd]=ws+S_BN+(size_t)(1+hd)*512; }
  stats_kernel<<<dim3(8,3),256,0,stream>>>(sa);
  // final outputs
  final_kernel<<<1,256,0,stream>>>(ws+HB1, ws+HB1+524288, ws+HB1+2*524288, ws+S_BN,
                                   hbg, hbb, actW, actB, tW, tB, rW, rB, out);
}

// Round 3
// 1021.058 us; speedup vs baseline: 5.3787x; 5.3787x over previous
//
#include <hip/hip_runtime.h>
#include <hip/hip_fp16.h>
#include <math.h>

#define Bn 32
#define Tn 64
#define Fdim 32
#define Gdim 32
#define Hdim 256
#define Ndim 20000
#define Cdim 32
#define G4 1024      // 4*H
#define BT 2048      // B*T
#define EPSc 1e-5f

__device__ __forceinline__ float sigmoidf_(float x){ return 1.0f/(1.0f + __expf(-x)); }
__device__ __forceinline__ float tanhf_(float x){ return 2.0f/(1.0f+__expf(-2.0f*x)) - 1.0f; }

typedef _Float16 h2t __attribute__((ext_vector_type(2)));

__device__ __forceinline__ float fdot2_(unsigned w, unsigned h, float acc){
#if defined(__has_builtin) && __has_builtin(__builtin_amdgcn_fdot2)
  return __builtin_amdgcn_fdot2(__builtin_bit_cast(h2t, w), __builtin_bit_cast(h2t, h), acc, false);
#else
  h2t a = __builtin_bit_cast(h2t, w), b = __builtin_bit_cast(h2t, h);
  acc = fmaf((float)a.x, (float)b.x, acc);
  return fmaf((float)a.y, (float)b.y, acc);
#endif
}

// ---- init workspace stats + lookup table -------------------------------
__global__ void init_kernel(float* ws){
  int i = blockIdx.x*256 + threadIdx.x;
  if (i < 2112) ws[i] = 0.0f;                  // gat stats (64) + bn stats (4*512)
  int* table = (int*)(ws + 2112);
  if (i < 40000) table[i] = 0x7fffffff;
}

// ---- gat_output mean/var reduction -------------------------------------
__global__ void bn_stats_kernel(const float* __restrict__ gat, float* __restrict__ sums){
  __shared__ float ss[256], sq[256];
  int tid = threadIdx.x;
  int idx = blockIdx.x*256 + tid;
  int stride = gridDim.x*256;
  const int total = Bn*Ndim*Gdim; // 20,480,000
  float s=0.f,q=0.f;
  for (int i=idx; i<total; i+=stride){ float v = gat[i]; s+=v; q+=v*v; }
  ss[tid]=s; sq[tid]=q; __syncthreads();
  for (int off=128; off>=32; off>>=1){
    if(tid<off){ ss[tid]+=ss[tid+off]; sq[tid]+=sq[tid+off]; }
    __syncthreads();
  }
  if (tid<32){ atomicAdd(&sums[tid], ss[tid]); atomicAdd(&sums[32+tid], sq[tid]); }
}

// ---- node id -> first index table --------------------------------------
__global__ void table_kernel(const int* __restrict__ node_ids, int* __restrict__ table){
  int i = blockIdx.x*256 + threadIdx.x;
  if (i < Ndim) atomicMin(&table[node_ids[i]], i);
}

// ---- gather + normalize + concat -> lstm_in (BT,64) --------------------
__global__ void build_input_kernel(const float* __restrict__ feats, const float* __restrict__ gat,
    const int* __restrict__ row_ids, const int* __restrict__ table, const float* __restrict__ sums,
    const float* __restrict__ bng, const float* __restrict__ bnb, float* __restrict__ out){
  int gt = blockIdx.x*256 + threadIdx.x;     // BT*64 total
  int pos = gt >> 6; int lane = gt & 63;
  float v;
  if (lane < 32){
    v = feats[pos*Fdim + lane];
  } else {
    int g = lane - 32;
    int r = row_ids[pos];
    int idx = table[r];
    if (idx < Ndim){
      int b = pos / Tn;
      float x = gat[(b*Ndim + idx)*Gdim + g];
      const float cnt = (float)(Bn*Ndim);
      float mean = sums[g]/cnt;
      float var  = sums[32+g]/cnt - mean*mean;
      v = (x-mean)*bng[g]*rsqrtf(var+EPSc) + bnb[g];
    } else v = 0.0f;
  }
  out[gt] = v;
}

// ---- transpose Wih matrices (1024,K) -> (K,1024) -----------------------
struct TArgs { const float* src[8]; float* dst[8]; int K[8]; };
__global__ void transpose_kernel(TArgs a){
  __shared__ float tile[32][33];
  int mat = blockIdx.y;
  int K = a.K[mat];
  int tc = blockIdx.x & 7; int tr = blockIdx.x >> 3;   // gridDim.x = 256
  if (tc*32 >= K) return;
  const float* src = a.src[mat]; float* dst = a.dst[mat];
  int tx = threadIdx.x; int ty = threadIdx.y;          // 32 x 8
  int r0 = tr*32, c0 = tc*32;
  #pragma unroll
  for (int i=0;i<4;i++){ int r = ty + i*8; tile[r][tx] = src[(r0+r)*K + c0+tx]; }
  __syncthreads();
  #pragma unroll
  for (int i=0;i<4;i++){ int r = ty + i*8; dst[(c0 + r)*G4 + r0 + tx] = tile[tx][r]; }
}

// ---- pack Whh matrices (1024,256) fp32 -> f16 pair-packed layout -------
// dst layout per matrix (131072 uints): index = (ci*1024 + tid)*4 + q,
// ci = c*8+i, tid = kq*256+j; element = pack(W[4j+c][k], W[4j+c][k+1]),
// k = kq*64 + 8i + 2q. Matches rec_kernel's coalesced uint4 preload.
struct PkArgs { const float* src[8]; };
__global__ void pack_kernel(PkArgs a, unsigned* __restrict__ dst){
  int gid = blockIdx.x*256 + threadIdx.x;   // 8*131072 total
  int m = gid >> 17;
  int rem = gid & 0x1FFFF;
  int q = rem & 3;
  int t2 = (rem >> 2) & 1023;
  int ci = rem >> 12;
  int c = ci >> 3, i = ci & 7;
  int j = t2 & 255, kq = t2 >> 8;
  int r = 4*j + c;
  int k = kq*64 + 8*i + 2*q;
  const float* W = a.src[m];
  float lo = W[r*256 + k], hi = W[r*256 + k + 1];
  unsigned ulo = (unsigned)__half_as_ushort(__float2half(lo));
  unsigned uhi = (unsigned)__half_as_ushort(__float2half(hi));
  dst[gid] = ulo | (uhi << 16);
}

// ---- input projection: out(m,1024) = x(m,K) @ WT(K,1024) + bias --------
struct PArgs { const float* x[3]; const float* wt[3]; const float* bias[3]; float* out[3]; int K; };
__global__ __launch_bounds__(256) void proj_kernel(PArgs a){
  int hd = blockIdx.z;
  int j  = blockIdx.y*256 + threadIdx.x;
  int m0 = blockIdx.x*4;
  const float* x  = a.x[hd];
  const float* wt = a.wt[hd];
  int K = a.K;
  float bv = a.bias[hd][j];
  float acc0=bv, acc1=bv, acc2=bv, acc3=bv;
  const float* x0 = x + m0*K;   // uniform addresses -> scalar loads
  #pragma unroll 4
  for (int k=0;k<K;k++){
    float w = wt[k*G4 + j];
    acc0 = fmaf(x0[k],     w, acc0);
    acc1 = fmaf(x0[K+k],   w, acc1);
    acc2 = fmaf(x0[2*K+k], w, acc2);
    acc3 = fmaf(x0[3*K+k], w, acc3);
  }
  float* out = a.out[hd] + m0*G4 + j;
  out[0]=acc0; out[G4]=acc1; out[2*G4]=acc2; out[3*G4]=acc3;
}

// ---- LSTM recurrence: one block per (batch, head), f16 weights ---------
// 1024 threads, thread (j=tid&255, kq=tid>>8) owns gate cols 4j..4j+3 for
// k-slice [64kq,64kq+64) = 32 f16 pairs per col: 24 pairs in VGPRs (96 regs,
// under the 128-reg cap at 4 waves/SIMD) + 8 pairs in LDS (128 KB).
// Per step: 8 uniform h-pair uint4 reads, 128 v_dot2_f32_f16, partials to
// LDS, 4-way reduce + activations by threads 0..255.
struct RArgs { const float* xp[3]; const unsigned* wt[3]; float* out[3]; };
__global__ __launch_bounds__(1024,1) void rec_kernel(RArgs a){
  extern __shared__ float lds[];
  unsigned* lw   = (unsigned*)lds;           // 32768 uints (128 KB) weights
  float*    part = lds + 32768;              // 4096 floats (16 KB) partials
  unsigned* hp   = (unsigned*)(lds + 36864); // 2 x 128 uints h packed pairs
  int b = blockIdx.x, hd = blockIdx.y, tid = threadIdx.x;
  int j = tid & 255, kq = tid >> 8;
  const float* xp = a.xp[hd] + (size_t)b*Tn*G4;
  const unsigned* wt = a.wt[hd];
  float* out = a.out[hd] + (size_t)b*Tn*Hdim;

  // preload: chunk ci=c*8+i holds 4 pairs/thread; i<6 -> regs, i>=6 -> LDS
  unsigned w[96];
  #pragma unroll
  for (int c=0;c<4;c++){
    #pragma unroll
    for (int i=0;i<6;i++){
      uint4 v = *(const uint4*)(wt + ((c*8+i)*1024 + tid)*4);
      w[(c*6+i)*4+0]=v.x; w[(c*6+i)*4+1]=v.y; w[(c*6+i)*4+2]=v.z; w[(c*6+i)*4+3]=v.w;
    }
    #pragma unroll
    for (int i=6;i<8;i++){
      uint4 v = *(const uint4*)(wt + ((c*8+i)*1024 + tid)*4);
      *(uint4*)(lw + ((c*2+(i-6))*1024 + tid)*4) = v;
    }
  }
  float cst = 0.0f;
  if (tid < 128){ hp[tid] = 0u; hp[128+tid] = 0u; }
  __syncthreads();

  int p = 0;
  for (int t=0; t<Tn; t++){
    float ac0, ac1, ac2, ac3;
    if (kq == 0){
      float4 xv = *(const float4*)(xp + t*G4 + 4*j);
      ac0=xv.x; ac1=xv.y; ac2=xv.z; ac3=xv.w;
    } else { ac0=0.f; ac1=0.f; ac2=0.f; ac3=0.f; }
    const unsigned* hrow = hp + p*128 + kq*32;
    #pragma unroll
    for (int ic=0; ic<6; ic++){
      uint4 hv = *(const uint4*)(hrow + 4*ic);
      ac0=fdot2_(w[0*24+ic*4+0],hv.x,ac0); ac0=fdot2_(w[0*24+ic*4+1],hv.y,ac0);
      ac0=fdot2_(w[0*24+ic*4+2],hv.z,ac0); ac0=fdot2_(w[0*24+ic*4+3],hv.w,ac0);
      ac1=fdot2_(w[1*24+ic*4+0],hv.x,ac1); ac1=fdot2_(w[1*24+ic*4+1],hv.y,ac1);
      ac1=fdot2_(w[1*24+ic*4+2],hv.z,ac1); ac1=fdot2_(w[1*24+ic*4+3],hv.w,ac1);
      ac2=fdot2_(w[2*24+ic*4+0],hv.x,ac2); ac2=fdot2_(w[2*24+ic*4+1],hv.y,ac2);
      ac2=fdot2_(w[2*24+ic*4+2],hv.z,ac2); ac2=fdot2_(w[2*24+ic*4+3],hv.w,ac2);
      ac3=fdot2_(w[3*24+ic*4+0],hv.x,ac3); ac3=fdot2_(w[3*24+ic*4+1],hv.y,ac3);
      ac3=fdot2_(w[3*24+ic*4+2],hv.z,ac3); ac3=fdot2_(w[3*24+ic*4+3],hv.w,ac3);
    }
    #pragma unroll
    for (int ic=6; ic<8; ic++){
      uint4 hv = *(const uint4*)(hrow + 4*ic);
      { uint4 lv = *(const uint4*)(lw + ((0*2+(ic-6))*1024 + tid)*4);
        ac0=fdot2_(lv.x,hv.x,ac0); ac0=fdot2_(lv.y,hv.y,ac0);
        ac0=fdot2_(lv.z,hv.z,ac0); ac0=fdot2_(lv.w,hv.w,ac0); }
      { uint4 lv = *(const uint4*)(lw + ((1*2+(ic-6))*1024 + tid)*4);
        ac1=fdot2_(lv.x,hv.x,ac1); ac1=fdot2_(lv.y,hv.y,ac1);
        ac1=fdot2_(lv.z,hv.z,ac1); ac1=fdot2_(lv.w,hv.w,ac1); }
      { uint4 lv = *(const uint4*)(lw + ((2*2+(ic-6))*1024 + tid)*4);
        ac2=fdot2_(lv.x,hv.x,ac2); ac2=fdot2_(lv.y,hv.y,ac2);
        ac2=fdot2_(lv.z,hv.z,ac2); ac2=fdot2_(lv.w,hv.w,ac2); }
      { uint4 lv = *(const uint4*)(lw + ((3*2+(ic-6))*1024 + tid)*4);
        ac3=fdot2_(lv.x,hv.x,ac3); ac3=fdot2_(lv.y,hv.y,ac3);
        ac3=fdot2_(lv.z,hv.z,ac3); ac3=fdot2_(lv.w,hv.w,ac3); }
    }
    *(float4*)(part + kq*1024 + 4*j) = make_float4(ac0,ac1,ac2,ac3);
    __syncthreads();
    if (tid < 256){
      int u = tid;
      float gi = part[u]     + part[1024+u]     + part[2048+u]     + part[3072+u];
      float gf = part[256+u] + part[1024+256+u] + part[2048+256+u] + part[3072+256+u];
      float gg = part[512+u] + part[1024+512+u] + part[2048+512+u] + part[3072+512+u];
      float go = part[768+u] + part[1024+768+u] + part[2048+768+u] + part[3072+768+u];
      cst = sigmoidf_(gf)*cst + sigmoidf_(gi)*tanhf_(gg);
      float h = sigmoidf_(go)*tanhf_(cst);
      out[t*Hdim + u] = h;
      float hpartner = __shfl_xor(h, 1);
      if ((u & 1) == 0){
        unsigned ulo = (unsigned)__half_as_ushort(__float2half(h));
        unsigned uhi = (unsigned)__half_as_ushort(__float2half(hpartner));
        hp[(p^1)*128 + (u>>1)] = ulo | (uhi << 16);
      }
    }
    __syncthreads();
    p ^= 1;
  }
}

// ---- per-feature mean/var stats over (B,T) -----------------------------
struct SArgs { const float* in[3]; float* stats[3]; };
__global__ void stats_kernel(SArgs a){
  int hd = blockIdx.y; int tid = threadIdx.x;
  const float* in = a.in[hd] + blockIdx.x*256*Hdim;
  float s=0.f,q=0.f;
  for (int r=0;r<256;r++){ float v = in[r*Hdim + tid]; s+=v; q+=v*v; }
  atomicAdd(&a.stats[hd][tid], s);
  atomicAdd(&a.stats[hd][Hdim+tid], q);
}

// ---- normalize shared output ------------------------------------------
__global__ void norm_kernel(const float* __restrict__ in, const float* __restrict__ stats,
   const float* __restrict__ g, const float* __restrict__ bta, float* __restrict__ out){
  int i = blockIdx.x*256 + threadIdx.x;
  int h = i & 255;
  float mean = stats[h]*(1.0f/BT);
  float var  = stats[Hdim+h]*(1.0f/BT) - mean*mean;
  out[i] = (in[i]-mean)*g[h]*rsqrtf(var+EPSc) + bta[h];
}

// ---- final: normalize last step of heads, fc + softmax -----------------
__global__ __launch_bounds__(256) void final_kernel(
  const float* __restrict__ h0, const float* __restrict__ h1, const float* __restrict__ h2,
  const float* __restrict__ stats,    // base ws+S_BN; head hd at (1+hd)*512
  const float* __restrict__ hbg, const float* __restrict__ hbb,
  const float* __restrict__ actW, const float* __restrict__ actB,
  const float* __restrict__ tW, const float* __restrict__ tB,
  const float* __restrict__ rW, const float* __restrict__ rB,
  float* __restrict__ outp){
  __shared__ float v0[Bn*Hdim];
  __shared__ float lg[Bn*Cdim];
  int tid = threadIdx.x;
  for (int i=tid; i<Bn*Hdim; i+=256){
    int b=i>>8, h=i&255;
    float sm = stats[512 + h], sq = stats[512+256+h];
    float mean = sm*(1.0f/BT); float var = sq*(1.0f/BT) - mean*mean;
    v0[i] = (h0[(b*Tn+63)*Hdim + h] - mean)*hbg[h]*rsqrtf(var+EPSc) + hbb[h];
  }
  __syncthreads();
  for (int i=tid; i<Bn*Cdim; i+=256){
    int b=i>>5, cc=i&31;
    float acc = actB[cc];
    const float* wrow = actW + cc*Hdim;
    const float* vrow = v0 + b*Hdim;
    #pragma unroll 4
    for (int h=0;h<Hdim;h++) acc = fmaf(vrow[h], wrow[h], acc);
    lg[i] = acc;
  }
  __syncthreads();
  if (tid < Bn){
    int b = tid;
    float m = -1e30f;
    #pragma unroll
    for (int cc=0; cc<Cdim; cc++) m = fmaxf(m, lg[b*Cdim+cc]);
    float e[Cdim]; float s = 0.f;
    #pragma unroll
    for (int cc=0; cc<Cdim; cc++){ float ee = __expf(lg[b*Cdim+cc]-m); e[cc]=ee; s+=ee; }
    float inv = 1.0f/s;
    #pragma unroll
    for (int cc=0; cc<Cdim; cc++) outp[b*Cdim+cc] = e[cc]*inv;
  }
  if (tid < 64){
    int b = tid & 31; int w = tid >> 5;
    const float* hh = w ? h2 : h1;
    const float* fw = w ? rW : tW;
    float fb = w ? rB[0] : tB[0];
    int hd = 1 + w;
    float acc = fb;
    for (int h=0; h<Hdim; h++){
      float sm = stats[(1+hd)*512 + h], sq = stats[(1+hd)*512+256+h];
      float mean = sm*(1.0f/BT); float var = sq*(1.0f/BT) - mean*mean;
      float v = (hh[(b*Tn+63)*Hdim + h] - mean)*hbg[hd*Hdim+h]*rsqrtf(var+EPSc) + hbb[hd*Hdim+h];
      acc = fmaf(v, fw[h], acc);
    }
    outp[1024 + w*32 + b] = acc;
  }
}

extern "C" void kernel_launch(void* const* d_in, const int* in_sizes, int n_in,
                              void* d_out, int out_size, void* d_ws, size_t ws_size,
                              hipStream_t stream){
  const float* data_feats = (const float*)d_in[0];
  const float* gat   = (const float*)d_in[1];
  const int*   row_ids  = (const int*)d_in[2];
  const int*   node_ids = (const int*)d_in[3];
  const float* sWih0 = (const float*)d_in[4];
  const float* sWhh0 = (const float*)d_in[5];
  const float* sb0   = (const float*)d_in[6];
  const float* sWih1 = (const float*)d_in[7];
  const float* sWhh1 = (const float*)d_in[8];
  const float* sb1   = (const float*)d_in[9];
  const float* hWih  = (const float*)d_in[10];
  const float* hWhh  = (const float*)d_in[11];
  const float* hb    = (const float*)d_in[12];
  const float* bng   = (const float*)d_in[13];
  const float* bnb   = (const float*)d_in[14];
  const float* bsg   = (const float*)d_in[15];
  const float* bsb   = (const float*)d_in[16];
  const float* hbg   = (const float*)d_in[17];
  const float* hbb   = (const float*)d_in[18];
  const float* actW  = (const float*)d_in[19];
  const float* actB  = (const float*)d_in[20];
  const float* tW    = (const float*)d_in[21];
  const float* tB    = (const float*)d_in[22];
  const float* rW    = (const float*)d_in[23];
  const float* rB    = (const float*)d_in[24];
  float* ws  = (float*)d_ws;
  float* out = (float*)d_out;

  // workspace layout (float offsets)
  const size_t S_GAT = 0;                       // 64
  const size_t S_BN  = 64;                      // 4*512
  const size_t TABLE = 2112;                    // 40000 ints
  const size_t TWOFF = 42112;                   // 8 slots x 262144 (Wih^T fp32)
  const size_t SLOT  = 262144;
  const size_t PKOFF = TWOFF + 8*SLOT;          // 8 slots x 131072 uints (Whh f16 packed)
  const size_t PSLOT = 131072;
  const size_t LSTM_IN = PKOFF + 8*PSLOT;       // 131072
  const size_t XPOFF   = LSTM_IN + 131072;      // 3 x 2,097,152
  const size_t BUF0 = XPOFF + 3*2097152;
  const size_t BUF1 = BUF0 + 524288;
  const size_t BUFN = BUF1 + 524288;
  const size_t HB0  = BUFN + 524288;
  const size_t HB1  = HB0 + 3*524288;           // end ~= 14.33M floats

  const int REC_LDS = 148480;                   // 128K weights + 16K part + 1K hp
  hipFuncSetAttribute((const void*)rec_kernel, hipFuncAttributeMaxDynamicSharedMemorySize, REC_LDS);

  init_kernel<<<157,256,0,stream>>>(ws);
  bn_stats_kernel<<<2048,256,0,stream>>>(gat, ws+S_GAT);
  table_kernel<<<(Ndim+255)/256,256,0,stream>>>(node_ids, (int*)(ws+TABLE));
  build_input_kernel<<<512,256,0,stream>>>(data_feats, gat, row_ids, (int*)(ws+TABLE),
                                           ws+S_GAT, bng, bnb, ws+LSTM_IN);

  // Wih transposes (fp32, for proj)
  TArgs ta;
  float* tw = ws + TWOFF;
  ta.src[0]=sWih0; ta.K[0]=64;
  ta.src[1]=sWih1; ta.K[1]=256;
  for (int hd=0; hd<3; hd++) for (int l=0;l<2;l++){
    ta.src[2+hd*2+l] = hWih + (size_t)(hd*2+l)*G4*Hdim; ta.K[2+hd*2+l] = 256;
  }
  for (int i=0;i<8;i++) ta.dst[i] = tw + i*SLOT;
  transpose_kernel<<<dim3(256,8),dim3(32,8),0,stream>>>(ta);

  // Whh f16 pack (for rec)
  unsigned* pk = (unsigned*)(ws + PKOFF);
  PkArgs pka;
  pka.src[0]=sWhh0; pka.src[1]=sWhh1;
  for (int hd=0; hd<3; hd++) for (int l=0;l<2;l++)
    pka.src[2+hd*2+l] = hWhh + (size_t)(hd*2+l)*G4*Hdim;
  pack_kernel<<<4096,256,0,stream>>>(pka, pk);

  PArgs pa; RArgs ra; SArgs sa;
  // shared layer 0
  pa.K=64; pa.x[0]=ws+LSTM_IN; pa.wt[0]=tw+0*SLOT; pa.bias[0]=sb0; pa.out[0]=ws+XPOFF;
  proj_kernel<<<dim3(512,4,1),256,0,stream>>>(pa);
  ra.xp[0]=ws+XPOFF; ra.wt[0]=pk+0*PSLOT; ra.out[0]=ws+BUF0;
  rec_kernel<<<dim3(32,1),1024,REC_LDS,stream>>>(ra);
  // shared layer 1
  pa.K=256; pa.x[0]=ws+BUF0; pa.wt[0]=tw+1*SLOT; pa.bias[0]=sb1; pa.out[0]=ws+XPOFF;
  proj_kernel<<<dim3(512,4,1),256,0,stream>>>(pa);
  ra.xp[0]=ws+XPOFF; ra.wt[0]=pk+1*PSLOT; ra.out[0]=ws+BUF1;
  rec_kernel<<<dim3(32,1),1024,REC_LDS,stream>>>(ra);
  // shared batchnorm
  sa.in[0]=ws+BUF1; sa.stats[0]=ws+S_BN;
  stats_kernel<<<dim3(8,1),256,0,stream>>>(sa);
  norm_kernel<<<2048,256,0,stream>>>(ws+BUF1, ws+S_BN, bsg, bsb, ws+BUFN);
  // heads layer 0
  pa.K=256;
  for (int hd=0;hd<3;hd++){
    pa.x[hd]=ws+BUFN; pa.wt[hd]=tw+(2+hd*2)*SLOT; pa.bias[hd]=hb + (size_t)(hd*2)*G4;
    pa.out[hd]=ws+XPOFF+(size_t)hd*2097152;
  }
  proj_kernel<<<dim3(512,4,3),256,0,stream>>>(pa);
  for (int hd=0;hd<3;hd++){
    ra.xp[hd]=ws+XPOFF+(size_t)hd*2097152; ra.wt[hd]=pk+(2+hd*2)*PSLOT; ra.out[hd]=ws+HB0+(size_t)hd*524288;
  }
  rec_kernel<<<dim3(32,3),1024,REC_LDS,stream>>>(ra);
  // heads layer 1
  for (int hd=0;hd<3;hd++){
    pa.x[hd]=ws+HB0+(size_t)hd*524288; pa.wt[hd]=tw+(2+hd*2+1)*SLOT; pa.bias[hd]=hb + (size_t)(hd*2+1)*G4;
    pa.out[hd]=ws+XPOFF+(size_t)hd*2097152;
  }
  proj_kernel<<<dim3(512,4,3),256,0,stream>>>(pa);
  for (int hd=0;hd<3;hd++){
    ra.xp[hd]=ws+XPOFF+(size_t)hd*2097152; ra.wt[hd]=pk+(2+hd*2+1)*PSLOT; ra.out[hd]=ws+HB1+(size_t)hd*524288;
  }
  rec_kernel<<<dim3(32,3),1024,REC_LDS,stream>>>(ra);
  // heads batchnorm stats
  for (int hd=0;hd<3;hd++){ sa.in[hd]=ws+HB1+(size_t)hd*524288; sa.stats[hd]=ws+S_BN+(size_t)(1+hd)*512; }
  stats_kernel<<<dim3(8,3),256,0,stream>>>(sa);
  // final outputs
  final_kernel<<<1,256,0,stream>>>(ws+HB1, ws+HB1+524288, ws+HB1+2*524288, ws+S_BN,
                                   hbg, hbb, actW, actB, tW, tB, rW, rB, out);
}

// Round 4
// 869.492 us; speedup vs baseline: 6.3163x; 1.1743x over previous
//
#include <hip/hip_runtime.h>
#include <hip/hip_fp16.h>
#include <math.h>

#define Bn 32
#define Tn 64
#define Fdim 32
#define Gdim 32
#define Hdim 256
#define Ndim 20000
#define Cdim 32
#define G4 1024      // 4*H
#define BT 2048      // B*T
#define EPSc 1e-5f

__device__ __forceinline__ float sigmoidf_(float x){ return 1.0f/(1.0f + __expf(-x)); }
__device__ __forceinline__ float tanhf_(float x){ return 2.0f/(1.0f+__expf(-2.0f*x)) - 1.0f; }

typedef _Float16 h2t __attribute__((ext_vector_type(2)));

__device__ __forceinline__ float fdot2_(unsigned w, unsigned h, float acc){
#if defined(__has_builtin) && __has_builtin(__builtin_amdgcn_fdot2)
  return __builtin_amdgcn_fdot2(__builtin_bit_cast(h2t, w), __builtin_bit_cast(h2t, h), acc, false);
#else
  h2t a = __builtin_bit_cast(h2t, w), b = __builtin_bit_cast(h2t, h);
  acc = fmaf((float)a.x, (float)b.x, acc);
  return fmaf((float)a.y, (float)b.y, acc);
#endif
}

__device__ __forceinline__ unsigned packh_(float lo, float hi){
  unsigned ulo = (unsigned)__half_as_ushort(__float2half(lo));
  unsigned uhi = (unsigned)__half_as_ushort(__float2half(hi));
  return ulo | (uhi << 16);
}

// ---- init workspace stats + lookup table -------------------------------
__global__ void init_kernel(float* ws){
  int i = blockIdx.x*256 + threadIdx.x;
  if (i < 2112) ws[i] = 0.0f;                  // gat stats (64) + bn stats (4*512)
  int* table = (int*)(ws + 2112);
  if (i < 40000) table[i] = 0x7fffffff;
}

// ---- gat_output mean/var reduction -------------------------------------
__global__ void bn_stats_kernel(const float* __restrict__ gat, float* __restrict__ sums){
  __shared__ float ss[256], sq[256];
  int tid = threadIdx.x;
  int idx = blockIdx.x*256 + tid;
  int stride = gridDim.x*256;
  const int total = Bn*Ndim*Gdim; // 20,480,000
  float s=0.f,q=0.f;
  for (int i=idx; i<total; i+=stride){ float v = gat[i]; s+=v; q+=v*v; }
  ss[tid]=s; sq[tid]=q; __syncthreads();
  for (int off=128; off>=32; off>>=1){
    if(tid<off){ ss[tid]+=ss[tid+off]; sq[tid]+=sq[tid+off]; }
    __syncthreads();
  }
  if (tid<32){ atomicAdd(&sums[tid], ss[tid]); atomicAdd(&sums[32+tid], sq[tid]); }
}

// ---- node id -> first index table --------------------------------------
__global__ void table_kernel(const int* __restrict__ node_ids, int* __restrict__ table){
  int i = blockIdx.x*256 + threadIdx.x;
  if (i < Ndim) atomicMin(&table[node_ids[i]], i);
}

// ---- gather + normalize + concat -> lstm_in packed f16 (BT,32 pairs) ---
__global__ void build_input_kernel(const float* __restrict__ feats, const float* __restrict__ gat,
    const int* __restrict__ row_ids, const int* __restrict__ table, const float* __restrict__ sums,
    const float* __restrict__ bng, const float* __restrict__ bnb, unsigned* __restrict__ out){
  int gt = blockIdx.x*256 + threadIdx.x;     // BT*32 total
  int pos = gt >> 5; int k2 = gt & 31;
  float lo, hi;
  if (k2 < 16){
    float2 v = *(const float2*)(feats + pos*Fdim + 2*k2);
    lo = v.x; hi = v.y;
  } else {
    int g0 = 2*(k2-16);
    int r = row_ids[pos];
    int idx = table[r];
    if (idx < Ndim){
      int b = pos / Tn;
      float2 x = *(const float2*)(gat + (size_t)(b*Ndim + idx)*Gdim + g0);
      const float cnt = (float)(Bn*Ndim);
      float m0 = sums[g0]/cnt,   v0 = sums[32+g0]/cnt - m0*m0;
      float m1 = sums[g0+1]/cnt, v1 = sums[32+g0+1]/cnt - m1*m1;
      lo = (x.x-m0)*bng[g0]*rsqrtf(v0+EPSc) + bnb[g0];
      hi = (x.y-m1)*bng[g0+1]*rsqrtf(v1+EPSc) + bnb[g0+1];
    } else { lo = 0.0f; hi = 0.0f; }
  }
  out[gt] = packh_(lo, hi);
}

// ---- pack+transpose Wih (1024,K) fp32 -> (K/2,1024) f16 pairs ----------
struct TArgs { const float* src[8]; unsigned* dst[8]; int K[8]; };
__global__ void packwih_kernel(TArgs a){
  __shared__ unsigned tile[32][33];
  int mat = blockIdx.y;
  int K = a.K[mat];
  int K2 = K >> 1;
  int ktiles = K2 >> 5;                  // 1 (K=64) or 4 (K=256)
  int tk = blockIdx.x & 3;               // k2-tile
  int tn = blockIdx.x >> 2;              // n-tile 0..31
  if (tk >= ktiles) return;
  const float* src = a.src[mat];
  unsigned* dst = a.dst[mat];
  int tx = threadIdx.x, ty = threadIdx.y;   // 32 x 8
  int n0 = tn*32, k2_0 = tk*32;
  #pragma unroll
  for (int i=0;i<4;i++){
    int nn = ty + 8*i;
    const float* p = src + (size_t)(n0+nn)*K + 2*(k2_0 + tx);
    tile[nn][tx] = packh_(p[0], p[1]);
  }
  __syncthreads();
  #pragma unroll
  for (int i=0;i<4;i++){
    int r = ty + 8*i;  // local k2
    dst[(size_t)(k2_0 + r)*G4 + n0 + tx] = tile[tx][r];
  }
}

// ---- pack Whh matrices (1024,256) fp32 -> f16 pair-packed layout -------
// (layout matches rec_kernel's coalesced uint4 preload; unchanged from r3)
struct PkArgs { const float* src[8]; };
__global__ void pack_kernel(PkArgs a, unsigned* __restrict__ dst){
  int gid = blockIdx.x*256 + threadIdx.x;   // 8*131072 total
  int m = gid >> 17;
  int rem = gid & 0x1FFFF;
  int q = rem & 3;
  int t2 = (rem >> 2) & 1023;
  int ci = rem >> 12;
  int c = ci >> 3, i = ci & 7;
  int j = t2 & 255, kq = t2 >> 8;
  int r = 4*j + c;
  int k = kq*64 + 8*i + 2*q;
  const float* W = a.src[m];
  dst[gid] = packh_(W[r*256 + k], W[r*256 + k + 1]);
}

// ---- input projection: out(m,1024) = x(m,K) @ WT(K,1024) + bias --------
// x packed f16 pairs [m][K2], w packed f16 pairs [k2][1024]. 8 m-rows per
// thread: 8 dot2 (16 MACs) per weight dword. x loads are wave-uniform ->
// scalar loads.
struct PArgs { const unsigned* x[3]; const unsigned* wt[3]; const float* bias[3]; float* out[3]; int K2; };
__global__ __launch_bounds__(256) void proj_kernel(PArgs a){
  int hd = blockIdx.z;
  int n  = blockIdx.y*256 + threadIdx.x;
  int m0 = blockIdx.x*8;
  int K2 = a.K2;
  const unsigned* xh = a.x[hd] + (size_t)m0*K2;
  const unsigned* wt = a.wt[hd];
  float bv = a.bias[hd][n];
  float acc[8];
  #pragma unroll
  for (int i=0;i<8;i++) acc[i]=bv;
  for (int k2=0;k2<K2;k2+=4){
    unsigned w0 = wt[(size_t)(k2+0)*G4+n];
    unsigned w1 = wt[(size_t)(k2+1)*G4+n];
    unsigned w2 = wt[(size_t)(k2+2)*G4+n];
    unsigned w3 = wt[(size_t)(k2+3)*G4+n];
    #pragma unroll
    for (int i=0;i<8;i++){
      uint4 xv = *(const uint4*)(xh + i*K2 + k2);   // uniform -> s_load_dwordx4
      acc[i]=fdot2_(w0,xv.x,acc[i]); acc[i]=fdot2_(w1,xv.y,acc[i]);
      acc[i]=fdot2_(w2,xv.z,acc[i]); acc[i]=fdot2_(w3,xv.w,acc[i]);
    }
  }
  float* out = a.out[hd] + (size_t)m0*G4 + n;
  #pragma unroll
  for (int i=0;i<8;i++) out[i*G4]=acc[i];
}

// ---- LSTM recurrence: one block per (batch, head), f16 weights ---------
// 1024 threads, thread (j=tid&255, kq=tid>>8) owns gate cols 4j..4j+3 for
// k-slice [64kq,64kq+64): 24 pairs in VGPRs + 8 pairs in LDS. Emits h both
// as fp32 (out) and packed f16 pairs (outh) for the next layer's proj.
struct RArgs { const float* xp[3]; const unsigned* wt[3]; float* out[3]; unsigned* outh[3]; };
__global__ __launch_bounds__(1024,1) void rec_kernel(RArgs a){
  extern __shared__ float lds[];
  unsigned* lw   = (unsigned*)lds;           // 32768 uints (128 KB) weights
  float*    part = lds + 32768;              // 4096 floats (16 KB) partials
  unsigned* hp   = (unsigned*)(lds + 36864); // 2 x 128 uints h packed pairs
  int b = blockIdx.x, hd = blockIdx.y, tid = threadIdx.x;
  int j = tid & 255, kq = tid >> 8;
  const float* xp = a.xp[hd] + (size_t)b*Tn*G4;
  const unsigned* wt = a.wt[hd];
  float* out = a.out[hd] + (size_t)b*Tn*Hdim;
  unsigned* outh = a.outh[hd] + (size_t)b*Tn*128;

  unsigned w[96];
  #pragma unroll
  for (int c=0;c<4;c++){
    #pragma unroll
    for (int i=0;i<6;i++){
      uint4 v = *(const uint4*)(wt + ((c*8+i)*1024 + tid)*4);
      w[(c*6+i)*4+0]=v.x; w[(c*6+i)*4+1]=v.y; w[(c*6+i)*4+2]=v.z; w[(c*6+i)*4+3]=v.w;
    }
    #pragma unroll
    for (int i=6;i<8;i++){
      uint4 v = *(const uint4*)(wt + ((c*8+i)*1024 + tid)*4);
      *(uint4*)(lw + ((c*2+(i-6))*1024 + tid)*4) = v;
    }
  }
  float cst = 0.0f;
  if (tid < 128){ hp[tid] = 0u; hp[128+tid] = 0u; }
  __syncthreads();

  int p = 0;
  for (int t=0; t<Tn; t++){
    float ac0, ac1, ac2, ac3;
    if (kq == 0){
      float4 xv = *(const float4*)(xp + t*G4 + 4*j);
      ac0=xv.x; ac1=xv.y; ac2=xv.z; ac3=xv.w;
    } else { ac0=0.f; ac1=0.f; ac2=0.f; ac3=0.f; }
    const unsigned* hrow = hp + p*128 + kq*32;
    #pragma unroll
    for (int ic=0; ic<6; ic++){
      uint4 hv = *(const uint4*)(hrow + 4*ic);
      ac0=fdot2_(w[0*24+ic*4+0],hv.x,ac0); ac0=fdot2_(w[0*24+ic*4+1],hv.y,ac0);
      ac0=fdot2_(w[0*24+ic*4+2],hv.z,ac0); ac0=fdot2_(w[0*24+ic*4+3],hv.w,ac0);
      ac1=fdot2_(w[1*24+ic*4+0],hv.x,ac1); ac1=fdot2_(w[1*24+ic*4+1],hv.y,ac1);
      ac1=fdot2_(w[1*24+ic*4+2],hv.z,ac1); ac1=fdot2_(w[1*24+ic*4+3],hv.w,ac1);
      ac2=fdot2_(w[2*24+ic*4+0],hv.x,ac2); ac2=fdot2_(w[2*24+ic*4+1],hv.y,ac2);
      ac2=fdot2_(w[2*24+ic*4+2],hv.z,ac2); ac2=fdot2_(w[2*24+ic*4+3],hv.w,ac2);
      ac3=fdot2_(w[3*24+ic*4+0],hv.x,ac3); ac3=fdot2_(w[3*24+ic*4+1],hv.y,ac3);
      ac3=fdot2_(w[3*24+ic*4+2],hv.z,ac3); ac3=fdot2_(w[3*24+ic*4+3],hv.w,ac3);
    }
    #pragma unroll
    for (int ic=6; ic<8; ic++){
      uint4 hv = *(const uint4*)(hrow + 4*ic);
      { uint4 lv = *(const uint4*)(lw + ((0*2+(ic-6))*1024 + tid)*4);
        ac0=fdot2_(lv.x,hv.x,ac0); ac0=fdot2_(lv.y,hv.y,ac0);
        ac0=fdot2_(lv.z,hv.z,ac0); ac0=fdot2_(lv.w,hv.w,ac0); }
      { uint4 lv = *(const uint4*)(lw + ((1*2+(ic-6))*1024 + tid)*4);
        ac1=fdot2_(lv.x,hv.x,ac1); ac1=fdot2_(lv.y,hv.y,ac1);
        ac1=fdot2_(lv.z,hv.z,ac1); ac1=fdot2_(lv.w,hv.w,ac1); }
      { uint4 lv = *(const uint4*)(lw + ((2*2+(ic-6))*1024 + tid)*4);
        ac2=fdot2_(lv.x,hv.x,ac2); ac2=fdot2_(lv.y,hv.y,ac2);
        ac2=fdot2_(lv.z,hv.z,ac2); ac2=fdot2_(lv.w,hv.w,ac2); }
      { uint4 lv = *(const uint4*)(lw + ((3*2+(ic-6))*1024 + tid)*4);
        ac3=fdot2_(lv.x,hv.x,ac3); ac3=fdot2_(lv.y,hv.y,ac3);
        ac3=fdot2_(lv.z,hv.z,ac3); ac3=fdot2_(lv.w,hv.w,ac3); }
    }
    *(float4*)(part + kq*1024 + 4*j) = make_float4(ac0,ac1,ac2,ac3);
    __syncthreads();
    if (tid < 256){
      int u = tid;
      float gi = part[u]     + part[1024+u]     + part[2048+u]     + part[3072+u];
      float gf = part[256+u] + part[1024+256+u] + part[2048+256+u] + part[3072+256+u];
      float gg = part[512+u] + part[1024+512+u] + part[2048+512+u] + part[3072+512+u];
      float go = part[768+u] + part[1024+768+u] + part[2048+768+u] + part[3072+768+u];
      cst = sigmoidf_(gf)*cst + sigmoidf_(gi)*tanhf_(gg);
      float h = sigmoidf_(go)*tanhf_(cst);
      out[t*Hdim + u] = h;
      float hpartner = __shfl_xor(h, 1);
      if ((u & 1) == 0){
        unsigned hh = packh_(h, hpartner);
        hp[(p^1)*128 + (u>>1)] = hh;
        outh[t*128 + (u>>1)] = hh;
      }
    }
    __syncthreads();
    p ^= 1;
  }
}

// ---- per-feature mean/var stats over (B,T) -----------------------------
struct SArgs { const float* in[3]; float* stats[3]; };
__global__ void stats_kernel(SArgs a){
  int hd = blockIdx.y; int tid = threadIdx.x;
  const float* in = a.in[hd] + blockIdx.x*256*Hdim;
  float s=0.f,q=0.f;
  for (int r=0;r<256;r++){ float v = in[r*Hdim + tid]; s+=v; q+=v*v; }
  atomicAdd(&a.stats[hd][tid], s);
  atomicAdd(&a.stats[hd][Hdim+tid], q);
}

// ---- normalize shared output -> packed f16 pairs for heads proj --------
__global__ void norm_kernel(const float* __restrict__ in, const float* __restrict__ stats,
   const float* __restrict__ g, const float* __restrict__ bta, unsigned* __restrict__ outh){
  int i2 = blockIdx.x*256 + threadIdx.x;   // BT*128 total
  int h2 = i2 & 127; int m = i2 >> 7;
  int h0 = 2*h2;
  float2 v = *(const float2*)(in + (size_t)m*Hdim + h0);
  float m0 = stats[h0]*(1.0f/BT),   v0 = stats[Hdim+h0]*(1.0f/BT) - m0*m0;
  float m1 = stats[h0+1]*(1.0f/BT), v1 = stats[Hdim+h0+1]*(1.0f/BT) - m1*m1;
  float lo = (v.x-m0)*g[h0]*rsqrtf(v0+EPSc) + bta[h0];
  float hi = (v.y-m1)*g[h0+1]*rsqrtf(v1+EPSc) + bta[h0+1];
  outh[i2] = packh_(lo, hi);
}

// ---- final: normalize last step of heads, fc + softmax -----------------
__global__ __launch_bounds__(256) void final_kernel(
  const float* __restrict__ h0, const float* __restrict__ h1, const float* __restrict__ h2,
  const float* __restrict__ stats,    // base ws+S_BN; head hd at (1+hd)*512
  const float* __restrict__ hbg, const float* __restrict__ hbb,
  const float* __restrict__ actW, const float* __restrict__ actB,
  const float* __restrict__ tW, const float* __restrict__ tB,
  const float* __restrict__ rW, const float* __restrict__ rB,
  float* __restrict__ outp){
  __shared__ float v0[Bn*Hdim];
  __shared__ float lg[Bn*Cdim];
  int tid = threadIdx.x;
  for (int i=tid; i<Bn*Hdim; i+=256){
    int b=i>>8, h=i&255;
    float sm = stats[512 + h], sq = stats[512+256+h];
    float mean = sm*(1.0f/BT); float var = sq*(1.0f/BT) - mean*mean;
    v0[i] = (h0[(b*Tn+63)*Hdim + h] - mean)*hbg[h]*rsqrtf(var+EPSc) + hbb[h];
  }
  __syncthreads();
  for (int i=tid; i<Bn*Cdim; i+=256){
    int b=i>>5, cc=i&31;
    float acc = actB[cc];
    const float* wrow = actW + cc*Hdim;
    const float* vrow = v0 + b*Hdim;
    #pragma unroll 4
    for (int h=0;h<Hdim;h++) acc = fmaf(vrow[h], wrow[h], acc);
    lg[i] = acc;
  }
  __syncthreads();
  if (tid < Bn){
    int b = tid;
    float m = -1e30f;
    #pragma unroll
    for (int cc=0; cc<Cdim; cc++) m = fmaxf(m, lg[b*Cdim+cc]);
    float e[Cdim]; float s = 0.f;
    #pragma unroll
    for (int cc=0; cc<Cdim; cc++){ float ee = __expf(lg[b*Cdim+cc]-m); e[cc]=ee; s+=ee; }
    float inv = 1.0f/s;
    #pragma unroll
    for (int cc=0; cc<Cdim; cc++) outp[b*Cdim+cc] = e[cc]*inv;
  }
  if (tid < 64){
    int b = tid & 31; int w = tid >> 5;
    const float* hh = w ? h2 : h1;
    const float* fw = w ? rW : tW;
    float fb = w ? rB[0] : tB[0];
    int hd = 1 + w;
    float acc = fb;
    for (int h=0; h<Hdim; h++){
      float sm = stats[(1+hd)*512 + h], sq = stats[(1+hd)*512+256+h];
      float mean = sm*(1.0f/BT); float var = sq*(1.0f/BT) - mean*mean;
      float v = (hh[(b*Tn+63)*Hdim + h] - mean)*hbg[hd*Hdim+h]*rsqrtf(var+EPSc) + hbb[hd*Hdim+h];
      acc = fmaf(v, fw[h], acc);
    }
    outp[1024 + w*32 + b] = acc;
  }
}

extern "C" void kernel_launch(void* const* d_in, const int* in_sizes, int n_in,
                              void* d_out, int out_size, void* d_ws, size_t ws_size,
                              hipStream_t stream){
  const float* data_feats = (const float*)d_in[0];
  const float* gat   = (const float*)d_in[1];
  const int*   row_ids  = (const int*)d_in[2];
  const int*   node_ids = (const int*)d_in[3];
  const float* sWih0 = (const float*)d_in[4];
  const float* sWhh0 = (const float*)d_in[5];
  const float* sb0   = (const float*)d_in[6];
  const float* sWih1 = (const float*)d_in[7];
  const float* sWhh1 = (const float*)d_in[8];
  const float* sb1   = (const float*)d_in[9];
  const float* hWih  = (const float*)d_in[10];
  const float* hWhh  = (const float*)d_in[11];
  const float* hb    = (const float*)d_in[12];
  const float* bng   = (const float*)d_in[13];
  const float* bnb   = (const float*)d_in[14];
  const float* bsg   = (const float*)d_in[15];
  const float* bsb   = (const float*)d_in[16];
  const float* hbg   = (const float*)d_in[17];
  const float* hbb   = (const float*)d_in[18];
  const float* actW  = (const float*)d_in[19];
  const float* actB  = (const float*)d_in[20];
  const float* tW    = (const float*)d_in[21];
  const float* tB    = (const float*)d_in[22];
  const float* rW    = (const float*)d_in[23];
  const float* rB    = (const float*)d_in[24];
  float* ws  = (float*)d_ws;
  float* out = (float*)d_out;

  // workspace layout (float offsets)
  const size_t S_GAT = 0;                         // 64
  const size_t S_BN  = 64;                        // 4*512
  const size_t TABLE = 2112;                      // 40000 ints
  const size_t WIHP  = 42112;                     // 8 slots x 131072 uints (Wih^T f16)
  const size_t PSLOT = 131072;
  const size_t WHHP  = WIHP + 8*PSLOT;            // 8 slots x 131072 uints (Whh f16)
  const size_t LSTM_INH = WHHP + 8*PSLOT;         // BT*32 uints
  const size_t XPOFF = LSTM_INH + 65536;          // 3 x 2,097,152 fp32
  const size_t BUF0H = XPOFF + 3*2097152;         // BT*128 uints (shared L0 h, f16)
  const size_t BUF1  = BUF0H + 262144;            // BT*256 fp32 (shared L1 h)
  const size_t BUFNH = BUF1 + 524288;             // BT*128 uints (normalized, f16)
  const size_t HB0H  = BUFNH + 262144;            // 3 x BT*128 uints (heads L0 h, f16)
  const size_t HB1   = HB0H + 3*262144;           // 3 x BT*256 fp32 (heads L1 h)

  const int REC_LDS = 148480;                     // 128K weights + 16K part + 1K hp
  hipFuncSetAttribute((const void*)rec_kernel, hipFuncAttributeMaxDynamicSharedMemorySize, REC_LDS);

  init_kernel<<<157,256,0,stream>>>(ws);
  bn_stats_kernel<<<2048,256,0,stream>>>(gat, ws+S_GAT);
  table_kernel<<<(Ndim+255)/256,256,0,stream>>>(node_ids, (int*)(ws+TABLE));
  build_input_kernel<<<256,256,0,stream>>>(data_feats, gat, row_ids, (int*)(ws+TABLE),
                                           ws+S_GAT, bng, bnb, (unsigned*)(ws+LSTM_INH));

  // Wih pack+transpose to f16 [k2][1024]
  unsigned* wih = (unsigned*)(ws + WIHP);
  TArgs ta;
  ta.src[0]=sWih0; ta.K[0]=64;
  ta.src[1]=sWih1; ta.K[1]=256;
  for (int hd=0; hd<3; hd++) for (int l=0;l<2;l++){
    ta.src[2+hd*2+l] = hWih + (size_t)(hd*2+l)*G4*Hdim; ta.K[2+hd*2+l] = 256;
  }
  for (int i=0;i<8;i++) ta.dst[i] = wih + (size_t)i*PSLOT;
  packwih_kernel<<<dim3(128,8),dim3(32,8),0,stream>>>(ta);

  // Whh f16 pack (for rec)
  unsigned* whh = (unsigned*)(ws + WHHP);
  PkArgs pka;
  pka.src[0]=sWhh0; pka.src[1]=sWhh1;
  for (int hd=0; hd<3; hd++) for (int l=0;l<2;l++)
    pka.src[2+hd*2+l] = hWhh + (size_t)(hd*2+l)*G4*Hdim;
  pack_kernel<<<4096,256,0,stream>>>(pka, whh);

  PArgs pa; RArgs ra; SArgs sa;
  // shared layer 0
  pa.K2=32; pa.x[0]=(unsigned*)(ws+LSTM_INH); pa.wt[0]=wih+0*PSLOT; pa.bias[0]=sb0; pa.out[0]=ws+XPOFF;
  proj_kernel<<<dim3(256,4,1),256,0,stream>>>(pa);
  ra.xp[0]=ws+XPOFF; ra.wt[0]=whh+0*PSLOT; ra.out[0]=ws+BUF1; /*dummy fp32*/ ra.outh[0]=(unsigned*)(ws+BUF0H);
  rec_kernel<<<dim3(32,1),1024,REC_LDS,stream>>>(ra);
  // shared layer 1
  pa.K2=128; pa.x[0]=(unsigned*)(ws+BUF0H); pa.wt[0]=wih+1*PSLOT; pa.bias[0]=sb1; pa.out[0]=ws+XPOFF;
  proj_kernel<<<dim3(256,4,1),256,0,stream>>>(pa);
  ra.xp[0]=ws+XPOFF; ra.wt[0]=whh+1*PSLOT; ra.out[0]=ws+BUF1; ra.outh[0]=(unsigned*)(ws+BUF0H); /*dummy f16*/
  rec_kernel<<<dim3(32,1),1024,REC_LDS,stream>>>(ra);
  // shared batchnorm
  sa.in[0]=ws+BUF1; sa.stats[0]=ws+S_BN;
  stats_kernel<<<dim3(8,1),256,0,stream>>>(sa);
  norm_kernel<<<1024,256,0,stream>>>(ws+BUF1, ws+S_BN, bsg, bsb, (unsigned*)(ws+BUFNH));
  // heads layer 0
  pa.K2=128;
  for (int hd=0;hd<3;hd++){
    pa.x[hd]=(unsigned*)(ws+BUFNH); pa.wt[hd]=wih+(size_t)(2+hd*2)*PSLOT; pa.bias[hd]=hb + (size_t)(hd*2)*G4;
    pa.out[hd]=ws+XPOFF+(size_t)hd*2097152;
  }
  proj_kernel<<<dim3(256,4,3),256,0,stream>>>(pa);
  for (int hd=0;hd<3;hd++){
    ra.xp[hd]=ws+XPOFF+(size_t)hd*2097152; ra.wt[hd]=whh+(size_t)(2+hd*2)*PSLOT;
    ra.out[hd]=ws+HB1+(size_t)hd*524288; /*dummy fp32*/ ra.outh[hd]=(unsigned*)(ws+HB0H)+(size_t)hd*262144;
  }
  rec_kernel<<<dim3(32,3),1024,REC_LDS,stream>>>(ra);
  // heads layer 1
  for (int hd=0;hd<3;hd++){
    pa.x[hd]=(unsigned*)(ws+HB0H)+(size_t)hd*262144; pa.wt[hd]=wih+(size_t)(2+hd*2+1)*PSLOT;
    pa.bias[hd]=hb + (size_t)(hd*2+1)*G4;
    pa.out[hd]=ws+XPOFF+(size_t)hd*2097152;
  }
  proj_kernel<<<dim3(256,4,3),256,0,stream>>>(pa);
  for (int hd=0;hd<3;hd++){
    ra.xp[hd]=ws+XPOFF+(size_t)hd*2097152; ra.wt[hd]=whh+(size_t)(2+hd*2+1)*PSLOT;
    ra.out[hd]=ws+HB1+(size_t)hd*524288; ra.outh[hd]=(unsigned*)(ws+HB0H)+(size_t)hd*262144; /*dummy f16*/
  }
  rec_kernel<<<dim3(32,3),1024,REC_LDS,stream>>>(ra);
  // heads batchnorm stats
  for (int hd=0;hd<3;hd++){ sa.in[hd]=ws+HB1+(size_t)hd*524288; sa.stats[hd]=ws+S_BN+(size_t)(1+hd)*512; }
  stats_kernel<<<dim3(8,3),256,0,stream>>>(sa);
  // final outputs
  final_kernel<<<1,256,0,stream>>>(ws+HB1, ws+HB1+524288, ws+HB1+2*524288, ws+S_BN,
                                   hbg, hbb, actW, actB, tW, tB, rW, rB, out);
}